// Round 1
// baseline (424.282 us; speedup 1.0000x reference)
//
#include <hip/hip_runtime.h>
#include <hip/hip_bf16.h>
#include <math.h>

// Hyperbolic (Poincare-ball) pairwise distance:
//   out[b,h,n,m] = arccosh(1 + 2*c*||q_n-k_m||^2 / ((1-c||q_n||^2)(1-c||k_m||^2)))
// c = 1.0. Shapes: q,k f32[4,8,2048,64] -> out f32[4,8,2048,2048].
//
// Strategy: per-(b,h) 128x128 output tiles; D=64 staged once in LDS as bf16;
// qk dot via mfma_f32_16x16x32_bf16; norms + epilogue in exact f32.
// Numerically stable arccosh(1+t) = log1p(t + sqrt(t*(t+2))).

typedef __bf16 bf16x8 __attribute__((ext_vector_type(8)));
typedef float f32x4 __attribute__((ext_vector_type(4)));

#define NSEQ 2048
#define DDIM 64
#define TILE 128
#define LDSW 72   // 64 + 8 bf16 pad -> row stride 144 B = 36 banks -> 2-way (free)

static __device__ __forceinline__ unsigned short f32_to_bf16_rne(float f) {
    unsigned int u = __builtin_bit_cast(unsigned int, f);
    u += 0x7fffu + ((u >> 16) & 1u);   // round-to-nearest-even
    return (unsigned short)(u >> 16);
}

__global__ __launch_bounds__(256, 2)
void hyp_dist_tile_kernel(const float* __restrict__ qg,
                          const float* __restrict__ kg,
                          float* __restrict__ outg)
{
    __shared__ __align__(16) unsigned short Qs[TILE * LDSW];
    __shared__ __align__(16) unsigned short Ks[TILE * LDSW];
    __shared__ float qn[TILE];
    __shared__ float kn[TILE];

    const int bid  = blockIdx.x;
    const int bh   = bid >> 8;    // 0..31  (B*H)
    const int tile = bid & 255;   // 16x16 tiles of 128x128
    const int tr   = tile >> 4;
    const int tc   = tile & 15;

    const int t    = threadIdx.x;  // 256 threads = 4 waves
    const int row  = t >> 1;       // 0..127
    const int half = t & 1;        // each thread: half a row (32 f32)

    // ---- stage Q tile (f32 -> bf16 LDS) + row norms in f32 ----
    {
        const float* src = qg + (((size_t)bh * NSEQ) + (size_t)(tr * TILE + row)) * DDIM
                              + half * 32;
        float partial = 0.f;
        #pragma unroll
        for (int i = 0; i < 8; ++i) {
            float4 v = reinterpret_cast<const float4*>(src)[i];
            partial += v.x * v.x + v.y * v.y + v.z * v.z + v.w * v.w;
            ushort4 b;
            b.x = f32_to_bf16_rne(v.x);
            b.y = f32_to_bf16_rne(v.y);
            b.z = f32_to_bf16_rne(v.z);
            b.w = f32_to_bf16_rne(v.w);
            *reinterpret_cast<ushort4*>(&Qs[row * LDSW + half * 32 + i * 4]) = b;
        }
        partial += __shfl_xor(partial, 1);
        if (half == 0) qn[row] = partial;
    }
    // ---- stage K tile ----
    {
        const float* src = kg + (((size_t)bh * NSEQ) + (size_t)(tc * TILE + row)) * DDIM
                              + half * 32;
        float partial = 0.f;
        #pragma unroll
        for (int i = 0; i < 8; ++i) {
            float4 v = reinterpret_cast<const float4*>(src)[i];
            partial += v.x * v.x + v.y * v.y + v.z * v.z + v.w * v.w;
            ushort4 b;
            b.x = f32_to_bf16_rne(v.x);
            b.y = f32_to_bf16_rne(v.y);
            b.z = f32_to_bf16_rne(v.z);
            b.w = f32_to_bf16_rne(v.w);
            *reinterpret_cast<ushort4*>(&Ks[row * LDSW + half * 32 + i * 4]) = b;
        }
        partial += __shfl_xor(partial, 1);
        if (half == 0) kn[row] = partial;
    }

    __syncthreads();

    // ---- MFMA: each wave computes a 64x64 sub-tile (4x4 frags of 16x16) ----
    const int wid   = t >> 6;
    const int lane  = t & 63;
    const int waveR = (wid >> 1) * 64;  // 2x2 wave grid
    const int waveC = (wid & 1) * 64;
    const int lr    = lane & 15;
    const int lg    = lane >> 4;

    f32x4 acc[4][4];
    #pragma unroll
    for (int i = 0; i < 4; ++i)
        #pragma unroll
        for (int j = 0; j < 4; ++j)
            acc[i][j] = (f32x4){0.f, 0.f, 0.f, 0.f};

    // A and B frags use the SAME contiguous-8-bf16 k mapping, so any HW k
    // permutation cancels in the dot product. Only C/D layout must be exact.
    #pragma unroll
    for (int ks = 0; ks < 2; ++ks) {
        bf16x8 af[4], bfr[4];
        #pragma unroll
        for (int f = 0; f < 4; ++f) {
            af[f]  = *reinterpret_cast<const bf16x8*>(
                         &Qs[(waveR + f * 16 + lr) * LDSW + ks * 32 + lg * 8]);
            bfr[f] = *reinterpret_cast<const bf16x8*>(
                         &Ks[(waveC + f * 16 + lr) * LDSW + ks * 32 + lg * 8]);
        }
        #pragma unroll
        for (int i = 0; i < 4; ++i)
            #pragma unroll
            for (int j = 0; j < 4; ++j)
                acc[i][j] = __builtin_amdgcn_mfma_f32_16x16x32_bf16(
                                af[i], bfr[j], acc[i][j], 0, 0, 0);
    }

    // ---- epilogue: C/D layout col=lane&15, row=(lane>>4)*4+reg (m89/m91) ----
    const size_t out_bh = (size_t)bh * NSEQ * NSEQ;
    #pragma unroll
    for (int i = 0; i < 4; ++i) {
        float qv[4], qd[4];
        #pragma unroll
        for (int r = 0; r < 4; ++r) {
            qv[r] = qn[waveR + i * 16 + lg * 4 + r];
            qd[r] = 1.f - qv[r];
        }
        #pragma unroll
        for (int j = 0; j < 4; ++j) {
            const int col_l  = waveC + j * 16 + lr;
            const float kv   = kn[col_l];
            const float kd   = 1.f - kv;
            const size_t gcol = (size_t)(tc * TILE + col_l);
            float* op = outg + out_bh
                      + (size_t)(tr * TILE + waveR + i * 16 + lg * 4) * NSEQ + gcol;
            #pragma unroll
            for (int r = 0; r < 4; ++r) {
                float dot  = acc[i][j][r];
                float diff = fmaxf(qv[r] + kv - 2.f * dot, 0.f);   // ||q-k||^2 >= 0
                float den  = fmaxf(qd[r] * kd, 1e-6f);
                float tt   = (2.f * diff) / den;                   // cosh_arg - 1 >= 0
                float y    = tt + sqrtf(tt * (tt + 2.f));
                op[(size_t)r * NSEQ] = log1pf(y);                  // arccosh, stable
            }
        }
    }
}

extern "C" void kernel_launch(void* const* d_in, const int* in_sizes, int n_in,
                              void* d_out, int out_size, void* d_ws, size_t ws_size,
                              hipStream_t stream) {
    const float* q = (const float*)d_in[0];
    const float* k = (const float*)d_in[1];
    float* out = (float*)d_out;
    // 32 (b,h) * 16 * 16 tiles of 128x128
    hyp_dist_tile_kernel<<<dim3(32 * 16 * 16), dim3(256), 0, stream>>>(q, k, out);
}

// Round 3
// 159.919 us; speedup vs baseline: 2.6531x; 2.6531x over previous
//
#include <hip/hip_runtime.h>
#include <hip/hip_bf16.h>
#include <math.h>

// Hyperbolic (Poincare-ball) pairwise distance:
//   out[b,h,n,m] = arccosh(1 + 2*c*||q_n-k_m||^2 / ((1-c||q_n||^2)(1-c||k_m||^2)))
// c = 1.0. Shapes: q,k f32[4,8,2048,64] -> out f32[4,8,2048,2048].
//
// R1 -> R2: kernel was VALU-bound (VALUBusy ~127, HBM 17%). Changes:
//  - precomputed reciprocal denominators in LDS (no per-element divide)
//  - fast HW sqrt/log2 (arccosh(1+t) = log2((1+t)+sqrt(t(t+2)))*ln2)
//  - swapped MFMA operands so each thread's 4 acc regs are 4 consecutive
//    output COLUMNS -> float4 non-temporal stores, 1024 B/wave-instr.
// R2 -> R3: fix compile error — __builtin_nontemporal_store needs an
//  ext_vector type, not HIP_vector_type<float,4>. Use f32x4 throughout.

typedef __bf16 bf16x8 __attribute__((ext_vector_type(8)));
typedef float f32x4 __attribute__((ext_vector_type(4)));

#define NSEQ 2048
#define DDIM 64
#define TILE 128
#define LDSW 72   // ushorts; 144 B row stride, keeps 16 B alignment for b128

static __device__ __forceinline__ unsigned short f32_to_bf16_rne(float f) {
    unsigned int u = __builtin_bit_cast(unsigned int, f);
    u += 0x7fffu + ((u >> 16) & 1u);   // round-to-nearest-even
    return (unsigned short)(u >> 16);
}

__global__ __launch_bounds__(256, 2)
void hyp_dist_tile_kernel(const float* __restrict__ qg,
                          const float* __restrict__ kg,
                          float* __restrict__ outg)
{
    __shared__ __align__(16) unsigned short Qs[TILE * LDSW];
    __shared__ __align__(16) unsigned short Ks[TILE * LDSW];
    __shared__ __align__(16) float qn[TILE];   // ||q||^2
    __shared__ __align__(16) float kn[TILE];   // ||k||^2
    __shared__ __align__(16) float qi2[TILE];  // 2/(1-||q||^2)
    __shared__ __align__(16) float ki[TILE];   // 1/(1-||k||^2)

    const int bid  = blockIdx.x;
    const int bh   = bid >> 8;    // 0..31  (B*H)
    const int tile = bid & 255;   // 16x16 tiles of 128x128
    const int tr   = tile >> 4;
    const int tc   = tile & 15;

    const int t    = threadIdx.x;  // 256 threads = 4 waves
    const int row  = t >> 1;       // 0..127
    const int half = t & 1;        // each thread: half a row (32 f32)

    // ---- stage Q tile (f32 -> bf16 LDS) + row norms / recips in f32 ----
    {
        const float* src = qg + (((size_t)bh * NSEQ) + (size_t)(tr * TILE + row)) * DDIM
                              + half * 32;
        float partial = 0.f;
        #pragma unroll
        for (int i = 0; i < 8; ++i) {
            float4 v = reinterpret_cast<const float4*>(src)[i];
            partial += v.x * v.x + v.y * v.y + v.z * v.z + v.w * v.w;
            ushort4 b;
            b.x = f32_to_bf16_rne(v.x);
            b.y = f32_to_bf16_rne(v.y);
            b.z = f32_to_bf16_rne(v.z);
            b.w = f32_to_bf16_rne(v.w);
            *reinterpret_cast<ushort4*>(&Qs[row * LDSW + half * 32 + i * 4]) = b;
        }
        partial += __shfl_xor(partial, 1);
        if (half == 0) {
            qn[row]  = partial;
            // per-factor clamp 1e-3 -> product >= 1e-6 (reference clamp level)
            qi2[row] = 2.f * __builtin_amdgcn_rcpf(fmaxf(1.f - partial, 1e-3f));
        }
    }
    // ---- stage K tile ----
    {
        const float* src = kg + (((size_t)bh * NSEQ) + (size_t)(tc * TILE + row)) * DDIM
                              + half * 32;
        float partial = 0.f;
        #pragma unroll
        for (int i = 0; i < 8; ++i) {
            float4 v = reinterpret_cast<const float4*>(src)[i];
            partial += v.x * v.x + v.y * v.y + v.z * v.z + v.w * v.w;
            ushort4 b;
            b.x = f32_to_bf16_rne(v.x);
            b.y = f32_to_bf16_rne(v.y);
            b.z = f32_to_bf16_rne(v.z);
            b.w = f32_to_bf16_rne(v.w);
            *reinterpret_cast<ushort4*>(&Ks[row * LDSW + half * 32 + i * 4]) = b;
        }
        partial += __shfl_xor(partial, 1);
        if (half == 0) {
            kn[row] = partial;
            ki[row] = __builtin_amdgcn_rcpf(fmaxf(1.f - partial, 1e-3f));
        }
    }

    __syncthreads();

    // ---- MFMA: each wave computes a 64x64 sub-tile (4x4 frags of 16x16) ----
    const int wid   = t >> 6;
    const int lane  = t & 63;
    const int waveR = (wid >> 1) * 64;  // 2x2 wave grid
    const int waveC = (wid & 1) * 64;
    const int lr    = lane & 15;
    const int lg    = lane >> 4;

    f32x4 acc[4][4];
    #pragma unroll
    for (int i = 0; i < 4; ++i)
        #pragma unroll
        for (int j = 0; j < 4; ++j)
            acc[i][j] = (f32x4){0.f, 0.f, 0.f, 0.f};

    // Operands SWAPPED vs R1: acc[i][j] = mfma(K_frag[j], Q_frag[i]) so that
    // D layout is q_idx = lane&15, k_idx = (lane>>4)*4 + reg  ->
    // 4 regs = 4 consecutive output columns (contiguous in memory).
    #pragma unroll
    for (int ks = 0; ks < 2; ++ks) {
        bf16x8 af[4], bfr[4];
        #pragma unroll
        for (int f = 0; f < 4; ++f) {
            af[f]  = *reinterpret_cast<const bf16x8*>(
                         &Qs[(waveR + f * 16 + lr) * LDSW + ks * 32 + lg * 8]);
            bfr[f] = *reinterpret_cast<const bf16x8*>(
                         &Ks[(waveC + f * 16 + lr) * LDSW + ks * 32 + lg * 8]);
        }
        #pragma unroll
        for (int i = 0; i < 4; ++i)
            #pragma unroll
            for (int j = 0; j < 4; ++j)
                acc[i][j] = __builtin_amdgcn_mfma_f32_16x16x32_bf16(
                                bfr[j], af[i], acc[i][j], 0, 0, 0);
    }

    // ---- epilogue: q_row = lane&15, k_col = (lane>>4)*4 + reg ----
    const size_t out_bh = (size_t)bh * NSEQ * NSEQ;
    const int    colb   = tc * TILE + waveC + lg * 4;   // thread's k-col base
    #pragma unroll
    for (int i = 0; i < 4; ++i) {
        const int   qrow = waveR + i * 16 + lr;
        const float qv   = qn[qrow];
        const float q2   = qi2[qrow];   // 2/(1-|q|^2)
        float* rowp = outg + out_bh + (size_t)(tr * TILE + qrow) * NSEQ + colb;
        #pragma unroll
        for (int j = 0; j < 4; ++j) {
            const int kbase = waveC + j * 16 + lg * 4;
            const f32x4 kv  = *reinterpret_cast<const f32x4*>(&kn[kbase]);
            const f32x4 kiv = *reinterpret_cast<const f32x4*>(&ki[kbase]);
            f32x4 res;
            #pragma unroll
            for (int r = 0; r < 4; ++r) {
                const float dot  = acc[i][j][r];
                const float diff = fmaxf(fmaf(-2.f, dot, qv + kv[r]), 0.f); // ||q-k||^2
                const float tt   = diff * (q2 * kiv[r]);                    // cosh_arg-1
                const float p    = tt * (tt + 2.f);
                const float sq   = __builtin_amdgcn_sqrtf(p);
                const float x    = (1.f + tt) + sq;                         // >= 1
                const float l2   = __builtin_amdgcn_logf(x);                // log2
                res[r] = l2 * 0.69314718055994531f;                         // -> ln
            }
            __builtin_nontemporal_store(res, reinterpret_cast<f32x4*>(rowp + j * 16));
        }
    }
}

extern "C" void kernel_launch(void* const* d_in, const int* in_sizes, int n_in,
                              void* d_out, int out_size, void* d_ws, size_t ws_size,
                              hipStream_t stream) {
    const float* q = (const float*)d_in[0];
    const float* k = (const float*)d_in[1];
    float* out = (float*)d_out;
    // 32 (b,h) * 16 * 16 tiles of 128x128
    hyp_dist_tile_kernel<<<dim3(32 * 16 * 16), dim3(256), 0, stream>>>(q, k, out);
}